// Round 13
// baseline (471.505 us; speedup 1.0000x reference)
//
#include <hip/hip_runtime.h>

#define TPB 256
typedef unsigned short u16;
typedef __attribute__((ext_vector_type(8))) short short8v;
typedef __attribute__((ext_vector_type(4))) float f32x4;

__device__ __forceinline__ u16 f2bf(float x) {
    unsigned u = __float_as_uint(x);
    return (u16)((u + 0x7FFFu + ((u >> 16) & 1u)) >> 16);
}
__device__ __forceinline__ float bf2f(u16 h) {
    return __uint_as_float(((unsigned)h) << 16);
}

// LDS 16B-chunk XOR swizzle (CS = chunks per row = CI/8).
template<int CS>
__device__ __forceinline__ int swzc(int r, int c) {
    constexpr int PH = (CS == 8) ? 0 : 1;
    return c ^ ((r >> PH) & (CS - 1));
}

// bijective XCD-contiguity swizzle (m204)
__device__ __forceinline__ int xcd_swz(int bid, int nwg) {
    int q = nwg >> 3, r = nwg & 7;
    int x = bid & 7, idx = bid >> 3;
    return (x < r ? x * (q + 1) : r * (q + 1) + (x - r) * q) + idx;
}

// async global->LDS, 16B per lane
__device__ __forceinline__ void gld16(const u16* g, u16* l) {
    __builtin_amdgcn_global_load_lds(
        (const __attribute__((address_space(1))) void*)g,
        (__attribute__((address_space(3))) void*)l, 16, 0, 0);
}

// ---- mean-VFE
__global__ void vfe_kernel(const float* __restrict__ voxels,
                           const int* __restrict__ nump,
                           float* __restrict__ x, int N) {
    int i = blockIdx.x * blockDim.x + threadIdx.x;
    if (i >= N * 4) return;
    int n = i >> 2, c = i & 3;
    const float* v = voxels + (long)n * 20 + c;
    float s = v[0] + v[4] + v[8] + v[12] + v[16];
    x[i] = s / fmaxf((float)nump[n], 1.0f);
}

// ---- fused invert-rulebook build: all 8 rulebooks in one dispatch
struct IBE { const int* rin; const int* rout; int* inv; int P, K, n_in, KP; };
struct IBA { IBE e[8]; };
__global__ void inv_build_all_kernel(IBA a, long grand) {
    long t = (long)blockIdx.x * blockDim.x + threadIdx.x;
    if (t >= grand) return;
    #pragma unroll
    for (int i = 0; i < 8; ++i) {
        if (t < a.e[i].KP) {
            const IBE& E = a.e[i];
            int ii = E.rin[t];
            if (ii != E.n_in) {
                int k = (int)(t / E.P);
                E.inv[(long)E.rout[t] * E.K + k] = ii;
            }
            return;
        }
        t -= a.e[i].KP;
    }
}

// ---- fused weight prep: 9 standard + 2 paired entries, one dispatch.
// standard: fp32 [K][ci][co] -> bf16 hi/lo [K][co][ci], swizzle baked in.
// paired (ci=16): fp32 [27][16][co] -> [14][co][32], tap-pairs on reduction
// axis, pseudo-tap 13 second half zero, swizzle baked in (cs=4, ph=1).
struct WPE { const float* w; u16* oh; u16* ol; int K, ci, co, total, paired; };
struct WPA { WPE e[11]; };
__global__ void wprep_kernel(WPA a, long grand) {
    long t = (long)blockIdx.x * blockDim.x + threadIdx.x;
    if (t >= grand) return;
    #pragma unroll
    for (int i = 0; i < 11; ++i) {
        if (t < a.e[i].total) {
            const WPE& E = a.e[i];
            if (E.paired) {
                int p = (int)(t / (E.co * 32));
                int rem = (int)(t % (E.co * 32));
                int o = rem / 32, ci = rem % 32;
                int tap = 2 * p + (ci >> 4);
                float x = (tap < 27) ? E.w[((long)tap * 16 + (ci & 15)) * E.co + o] : 0.f;
                u16 h = f2bf(x);
                float lf = x - bf2f(h);
                int ch = ci >> 3, e = ci & 7;
                int sch = ch ^ ((o >> 1) & 3);
                long d = ((long)p * E.co + o) * 32 + sch * 8 + e;
                E.oh[d] = h; E.ol[d] = f2bf(lf);
            } else {
                int cc = E.ci * E.co;
                int k = (int)(t / cc), r = (int)(t % cc), c = r / E.co, o = r % E.co;
                float x = E.w[t];
                u16 h = f2bf(x);
                float lf = x - bf2f(h);
                int cs = E.ci >> 3, ph = (cs == 8) ? 0 : 1;
                int ch = c >> 3, e = c & 7;
                int sch = ch ^ ((o >> ph) & (cs - 1));
                long d = ((long)k * E.co + o) * E.ci + sch * 8 + e;
                E.oh[d] = h; E.ol[d] = f2bf(lf);
            }
            return;
        }
        t -= a.e[i].total;
    }
}

// ---- direct tiny-CI conv (layer 0), emits bf16 hi/lo planes
template<int CO, int K>
__global__ __launch_bounds__(256)
void dconv4_kernel(const float* __restrict__ feats,
                   const float* __restrict__ w,
                   const float* __restrict__ bn,
                   const int* __restrict__ inv,
                   u16* __restrict__ oh, u16* __restrict__ ol,
                   int n_out) {
    constexpr int OG = CO / 4;
    __shared__ float sW[K * 4 * CO];
    for (int i = threadIdx.x; i < K * 4 * CO; i += 256) sW[i] = w[i];
    __syncthreads();
    long t = (long)blockIdx.x * 256 + threadIdx.x;
    int row = (int)(t / OG), og = (int)(t % OG);
    if (row >= n_out) return;
    float a0 = 0.f, a1 = 0.f, a2 = 0.f, a3 = 0.f;
    for (int k = 0; k < K; ++k) {
        int idx = inv[(long)row * K + k];
        if (idx < 0) continue;
        float4 av = *(const float4*)(feats + (long)idx * 4);
        const float* wk = sW + k * 4 * CO + og * 4;
        #pragma unroll
        for (int ci = 0; ci < 4; ++ci) {
            float a = (&av.x)[ci];
            a0 = fmaf(a, wk[ci * CO + 0], a0);
            a1 = fmaf(a, wk[ci * CO + 1], a1);
            a2 = fmaf(a, wk[ci * CO + 2], a2);
            a3 = fmaf(a, wk[ci * CO + 3], a3);
        }
    }
    float4 g = *(const float4*)(bn + og * 4);
    float4 b = *(const float4*)(bn + CO + og * 4);
    float4 m = *(const float4*)(bn + 2 * CO + og * 4);
    float4 v = *(const float4*)(bn + 3 * CO + og * 4);
    float o4[4];
    o4[0] = fmaxf((a0 - m.x) * rsqrtf(v.x + 1e-3f) * g.x + b.x, 0.f);
    o4[1] = fmaxf((a1 - m.y) * rsqrtf(v.y + 1e-3f) * g.y + b.y, 0.f);
    o4[2] = fmaxf((a2 - m.z) * rsqrtf(v.z + 1e-3f) * g.z + b.z, 0.f);
    o4[3] = fmaxf((a3 - m.w) * rsqrtf(v.w + 1e-3f) * g.w + b.w, 0.f);
    long base = (long)row * CO + og * 4;
    #pragma unroll
    for (int c = 0; c < 4; ++c) {
        u16 h = f2bf(o4[c]);
        oh[base + c] = h;
        ol[base + c] = f2bf(o4[c] - bf2f(h));
    }
}

// ---- MFMA sparse conv: single-buffer gld16 staging, 2 barriers/tap,
// XOR-swizzled LDS, inv read directly (L2-hot). ROWS = output rows per
// block (64 or 128); ROWS=128 halves B bytes per MFMA and doubles compute
// per barrier-stall (split-K deepens to keep TLP). EPI: 0 = fp32 partials
// to slab; 1 = fused BN+ReLU+bf16 planes (ys==1); 2 = fused fp32 out.
template<int CI, int CO, int ROWS, int KPt, int KT, bool PAIRED, int EPI>
__global__ __launch_bounds__(256, 4)
void mconv_kernel(const u16* __restrict__ fh, const u16* __restrict__ fl,
                  const u16* __restrict__ wh, const u16* __restrict__ wl,
                  const int* __restrict__ inv,
                  const u16* __restrict__ zpage,
                  float* __restrict__ part, long slab_elems,
                  const float* __restrict__ bn,
                  u16* __restrict__ oh, u16* __restrict__ ol,
                  float* __restrict__ outf,
                  int n_out, int kpb) {
    constexpr int CS  = CI / 8;
    constexpr int LCS = (CS == 8) ? 3 : 2;
    constexpr int PH  = (CS == 8) ? 0 : 1;
    constexpr int KS  = CI / 32;
    constexpr int WC  = (ROWS == 128) ? 1 : ((CO >= 32) ? 2 : 1);  // wave cols
    constexpr int WRW = 4 / WC;                                    // waves along rows
    constexpr int MT  = ROWS / (16 * WRW);                         // 16-row tiles/wave
    constexpr int NTW = CO / (16 * WC);                            // 16-col tiles/wave
    constexpr int ASL = ROWS * CS;
    constexpr int BSL = CO * CS;
    constexpr int AIT = (ASL + 255) / 256;
    constexpr int BIT = (BSL + 255) / 256;

    __shared__ __align__(16) u16 sAh[ROWS * CI];
    __shared__ __align__(16) u16 sAl[ROWS * CI];
    __shared__ __align__(16) u16 sBh[CO * CI];
    __shared__ __align__(16) u16 sBl[CO * CI];

    const int t = threadIdx.x;
    const int bx = xcd_swz(blockIdx.x, gridDim.x);
    const int brow = bx * ROWS;
    const int kbeg = blockIdx.y * kpb;
    const int kend = (kbeg + kpb < KPt) ? (kbeg + kpb) : KPt;

    const int lane = t & 63, wid = t >> 6;
    const int wr = wid / WC, wc = wid % WC;
    const int frow = lane & 15;
    const int fch  = lane >> 4;

    f32x4 acc[MT][NTW];
    #pragma unroll
    for (int mt = 0; mt < MT; ++mt)
        #pragma unroll
        for (int nt = 0; nt < NTW; ++nt) {
            acc[mt][nt][0] = 0.f; acc[mt][nt][1] = 0.f;
            acc[mt][nt][2] = 0.f; acc[mt][nt][3] = 0.f;
        }

    auto stage = [&](int k) {
        #pragma unroll
        for (int s = 0; s < AIT; ++s) {
            int slot = s * 256 + t;
            if (ASL % 256 == 0 || slot < ASL) {
                int r = slot >> LCS, cc = slot & (CS - 1);
                int c = cc ^ ((r >> PH) & (CS - 1));
                int grow = brow + r;
                const u16 *srcH, *srcL;
                if (PAIRED) {
                    int tap = 2 * k + (c >> 1);
                    int idx = (grow < n_out && tap < KT)
                              ? inv[(long)grow * KT + tap] : -1;
                    srcH = (idx >= 0) ? fh + (long)idx * 16 + (c & 1) * 8 : zpage;
                    srcL = (idx >= 0) ? fl + (long)idx * 16 + (c & 1) * 8 : zpage;
                } else {
                    int idx = (grow < n_out) ? inv[(long)grow * KT + k] : -1;
                    srcH = (idx >= 0) ? fh + (long)idx * CI + c * 8 : zpage;
                    srcL = (idx >= 0) ? fl + (long)idx * CI + c * 8 : zpage;
                }
                gld16(srcH, sAh + (s * 256 + wid * 64) * 8);
                gld16(srcL, sAl + (s * 256 + wid * 64) * 8);
            }
        }
        const u16* gbh = wh + (long)k * CO * CI;
        const u16* gbl = wl + (long)k * CO * CI;
        #pragma unroll
        for (int s = 0; s < BIT; ++s) {
            int slot = s * 256 + t;
            if (BSL % 256 == 0 || slot < BSL) {
                gld16(gbh + (long)slot * 8, sBh + (s * 256 + wid * 64) * 8);
                gld16(gbl + (long)slot * 8, sBl + (s * 256 + wid * 64) * 8);
            }
        }
    };
    auto compute = [&]() {
        #pragma unroll
        for (int ks = 0; ks < KS; ++ks) {
            int c = ks * 4 + fch;
            short8v ah[MT], al[MT];
            #pragma unroll
            for (int mt = 0; mt < MT; ++mt) {
                int r = wr * (MT * 16) + mt * 16 + frow;
                int o = r * CI + swzc<CS>(r, c) * 8;
                ah[mt] = *(const short8v*)(sAh + o);
                al[mt] = *(const short8v*)(sAl + o);
            }
            #pragma unroll
            for (int nt = 0; nt < NTW; ++nt) {
                int col = wc * (CO / WC) + nt * 16 + frow;
                int o = col * CI + swzc<CS>(col, c) * 8;
                short8v bh = *(const short8v*)(sBh + o);
                short8v bl = *(const short8v*)(sBl + o);
                #pragma unroll
                for (int mt = 0; mt < MT; ++mt) {
                    acc[mt][nt] = __builtin_amdgcn_mfma_f32_16x16x32_bf16(ah[mt], bh, acc[mt][nt], 0, 0, 0);
                    acc[mt][nt] = __builtin_amdgcn_mfma_f32_16x16x32_bf16(ah[mt], bl, acc[mt][nt], 0, 0, 0);
                    acc[mt][nt] = __builtin_amdgcn_mfma_f32_16x16x32_bf16(al[mt], bh, acc[mt][nt], 0, 0, 0);
                }
            }
        }
    };

    for (int k = kbeg; k < kend; ++k) {
        stage(k);
        __syncthreads();                        // drains vmcnt -> LDS staged
        compute();
        if (k + 1 < kend) __syncthreads();
    }

    if constexpr (EPI == 0) {
        float* dst = part + (long)blockIdx.y * slab_elems;
        #pragma unroll
        for (int mt = 0; mt < MT; ++mt) {
            int orow0 = brow + wr * (MT * 16) + mt * 16 + (lane >> 4) * 4;
            #pragma unroll
            for (int nt = 0; nt < NTW; ++nt) {
                int ocol = wc * (CO / WC) + nt * 16 + (lane & 15);
                #pragma unroll
                for (int j = 0; j < 4; ++j) {
                    int r = orow0 + j;
                    if (r < n_out) dst[(long)r * CO + ocol] = acc[mt][nt][j];
                }
            }
        }
    } else {
        #pragma unroll
        for (int mt = 0; mt < MT; ++mt) {
            int orow0 = brow + wr * (MT * 16) + mt * 16 + (lane >> 4) * 4;
            #pragma unroll
            for (int nt = 0; nt < NTW; ++nt) {
                int ocol = wc * (CO / WC) + nt * 16 + (lane & 15);
                float g = bn[ocol], bb = bn[CO + ocol];
                float m = bn[2 * CO + ocol], vv = bn[3 * CO + ocol];
                float sc = rsqrtf(vv + 1e-3f) * g;
                #pragma unroll
                for (int j = 0; j < 4; ++j) {
                    int r = orow0 + j;
                    if (r < n_out) {
                        float yv = fmaxf((acc[mt][nt][j] - m) * sc + bb, 0.f);
                        if constexpr (EPI == 1) {
                            u16 h = f2bf(yv);
                            oh[(long)r * CO + ocol] = h;
                            ol[(long)r * CO + ocol] = f2bf(yv - bf2f(h));
                        } else {
                            outf[(long)r * CO + ocol] = yv;
                        }
                    }
                }
            }
        }
    }
}

// ---- slab reduce + BN + ReLU (+ bf16 hi/lo emit OR fp32 out)
template<bool EMIT16>
__global__ void reduce_bnrelu_kernel(const float* __restrict__ part, long stride,
                                     int ys, const float* __restrict__ bn, int co,
                                     float* __restrict__ outf,
                                     u16* __restrict__ oh, u16* __restrict__ ol,
                                     long total) {
    long t = (long)blockIdx.x * blockDim.x + threadIdx.x;
    if (t >= total) return;
    float s = 0.f;
    for (int y = 0; y < ys; ++y) s += part[(long)y * stride + t];
    int o = (int)(t % co);
    float g = bn[o], b = bn[co + o], m = bn[2 * co + o], v = bn[3 * co + o];
    float yv = fmaxf((s - m) * rsqrtf(v + 1e-3f) * g + b, 0.f);
    if (EMIT16) {
        u16 h = f2bf(yv);
        oh[t] = h;
        ol[t] = f2bf(yv - bf2f(h));
    } else {
        outf[t] = yv;
    }
}

// ---- per-batch max pool
__global__ void segmax_kernel(const float* __restrict__ x,
                              const int* __restrict__ bidx,
                              float* __restrict__ out, int rows, int nb) {
    __shared__ float sM[8 * 128];
    for (int i = threadIdx.x; i < nb * 128; i += 256) sM[i] = 0.f;
    __syncthreads();
    int c = threadIdx.x & 127;
    int sub = threadIdx.x >> 7;
    for (int r = blockIdx.x * 2 + sub; r < rows; r += gridDim.x * 2) {
        float v = x[(long)r * 128 + c];
        int b = bidx[r];
        atomicMax((int*)&sM[b * 128 + c], __float_as_int(v));
    }
    __syncthreads();
    for (int i = threadIdx.x; i < nb * 128; i += 256)
        atomicMax((int*)out + i, __float_as_int(sM[i]));
}

extern "C" void kernel_launch(void* const* d_in, const int* in_sizes, int n_in,
                              void* d_out, int out_size, void* d_ws, size_t ws_size,
                              hipStream_t stream) {
    (void)n_in;
    const float* voxels = (const float*)d_in[24];
    const int*   nump   = (const int*)d_in[25];
    const int N  = in_sizes[25];
    const int n2 = in_sizes[30] / 27;
    const int n3 = in_sizes[34] / 27;
    const int n4 = in_sizes[38] / 27;
    const int n5 = in_sizes[42];

    struct L { int wi, rb, K, ci, co, nin, nout; };
    const L layers[12] = {
        {0,  26, 27,  4,  16, N,  N }, {1,  26, 27, 16,  16, N,  N },
        {2,  28, 27, 16,  32, N,  n2}, {3,  30, 27, 32,  32, n2, n2},
        {4,  30, 27, 32,  32, n2, n2}, {5,  32, 27, 32,  64, n2, n3},
        {6,  34, 27, 64,  64, n3, n3}, {7,  34, 27, 64,  64, n3, n3},
        {8,  36, 27, 64,  64, n3, n4}, {9,  38, 27, 64,  64, n4, n4},
        {10, 38, 27, 64,  64, n4, n4}, {11, 40,  3, 64, 128, n4, n5},
    };
    struct RBD { int rb, K, nin, nout; };
    const RBD rbs[8] = {
        {26, 27, N,  N }, {28, 27, N,  n2}, {30, 27, n2, n2}, {32, 27, n2, n3},
        {34, 27, n3, n3}, {36, 27, n3, n4}, {38, 27, n4, n4}, {40, 3,  n4, n5},
    };
    const int invmap[12] = {0, 0, 1, 2, 2, 3, 4, 4, 5, 6, 6, 7};
    const int rowsv[12]  = {64, 64, 64, 64, 64, 128, 128, 128, 128, 128, 128, 64};

    // ---- workspace carve-up
    size_t feat_elems = (size_t)N * 4, wt_elems = 0, arena_elems = 0;
    for (int i = 0; i < 12; ++i) {
        size_t fe = (size_t)layers[i].nout * layers[i].co;
        if (fe > feat_elems) feat_elems = fe;
        if (i >= 3) wt_elems += (size_t)layers[i].K * layers[i].ci * layers[i].co;
    }
    for (int r = 0; r < 8; ++r) arena_elems += (size_t)rbs[r].nout * rbs[r].K;
    const size_t wp1_elems = 14 * 32 * 16;
    const size_t wp2_elems = 14 * 32 * 32;
    auto al = [](size_t x) { return (x + 255) & ~(size_t)255; };
    char* p = (char*)d_ws;
    u16*   zpage = (u16*)p; p += 256;
    int*   inv_arena = (int*)p; p += al(arena_elems * 4);
    float* bufA = (float*)p; p += al(feat_elems * 4);
    u16* ph[2]; u16* pl[2];
    ph[0] = (u16*)p; p += al(feat_elems * 2);
    pl[0] = (u16*)p; p += al(feat_elems * 2);
    ph[1] = (u16*)p; p += al(feat_elems * 2);
    pl[1] = (u16*)p; p += al(feat_elems * 2);
    u16* wth = (u16*)p; p += al(wt_elems * 2);
    u16* wtl = (u16*)p; p += al(wt_elems * 2);
    u16* wp1h = (u16*)p; p += al(wp1_elems * 2);
    u16* wp1l = (u16*)p; p += al(wp1_elems * 2);
    u16* wp2h = (u16*)p; p += al(wp2_elems * 2);
    u16* wp2l = (u16*)p; p += al(wp2_elems * 2);
    float* slab = (float*)p;
    size_t slab_budget = ws_size - (size_t)((char*)slab - (char*)d_ws);

    hipMemsetAsync(zpage, 0, 256, stream);

    // ---- inv arena: one memset + ONE fused build dispatch
    int* invs[8];
    {
        size_t off = 0;
        for (int r = 0; r < 8; ++r) { invs[r] = inv_arena + off; off += (size_t)rbs[r].nout * rbs[r].K; }
        hipMemsetAsync(inv_arena, 0xFF, arena_elems * sizeof(int), stream);
        IBA ia;
        long grand = 0;
        for (int r = 0; r < 8; ++r) {
            int P  = in_sizes[rbs[r].rb] / rbs[r].K;
            ia.e[r].rin  = (const int*)d_in[rbs[r].rb];
            ia.e[r].rout = (const int*)d_in[rbs[r].rb + 1];
            ia.e[r].inv  = invs[r];
            ia.e[r].P = P; ia.e[r].K = rbs[r].K; ia.e[r].n_in = rbs[r].nin;
            ia.e[r].KP = rbs[r].K * P;
            grand += ia.e[r].KP;
        }
        inv_build_all_kernel<<<dim3((unsigned)((grand + TPB - 1) / TPB)), dim3(TPB), 0, stream>>>(ia, grand);
    }

    // ---- VFE
    {
        long tot = (long)N * 4;
        vfe_kernel<<<dim3((unsigned)((tot + TPB - 1) / TPB)), dim3(TPB), 0, stream>>>(
            voxels, nump, bufA, N);
    }

    // ---- fused weight prep (9 standard + 2 paired)
    size_t woff[9];
    {
        WPA wa;
        size_t off = 0;
        for (int i = 0; i < 9; ++i) {
            const L& l = layers[i + 3];
            woff[i] = off;
            wa.e[i].w  = (const float*)d_in[2 * l.wi];
            wa.e[i].oh = wth + off;
            wa.e[i].ol = wtl + off;
            wa.e[i].K = l.K; wa.e[i].ci = l.ci; wa.e[i].co = l.co;
            wa.e[i].total = l.K * l.ci * l.co;
            wa.e[i].paired = 0;
            off += (size_t)wa.e[i].total;
        }
        wa.e[9]  = { (const float*)d_in[2], wp1h, wp1l, 27, 16, 16, (int)wp1_elems, 1 };
        wa.e[10] = { (const float*)d_in[4], wp2h, wp2l, 27, 16, 32, (int)wp2_elems, 1 };
        long grand = (long)off + wp1_elems + wp2_elems;
        wprep_kernel<<<dim3((unsigned)((grand + TPB - 1) / TPB)), dim3(TPB), 0, stream>>>(wa, grand);
    }

    // ---- layer 0
    {
        const L& l = layers[0];
        long tot = (long)l.nout * 4;
        dconv4_kernel<16, 27><<<dim3((unsigned)((tot + 255) / 256)), 256, 0, stream>>>(
            bufA, (const float*)d_in[0], (const float*)d_in[1], invs[0],
            ph[0], pl[0], l.nout);
    }

    // ---- layers 1-11
    int cset = 0;
    for (int i = 1; i < 12; ++i) {
        const L& l = layers[i];
        const int* invp = invs[invmap[i]];
        int ROWS = rowsv[i];
        unsigned blocks = (unsigned)((l.nout + ROWS - 1) / ROWS);
        int KPv = (i <= 2) ? 14 : l.K;
        int ysmax = (KPv == 14) ? 9 : ((KPv == 27) ? 27 : 3);
        size_t per = (size_t)l.nout * l.co * 4;
        int ys = 1;
        while (ys < ysmax && blocks * (unsigned)ys < 768) ys *= 3;
        if (ys > ysmax) ys = ysmax;
        while (ys > 1 && (size_t)ys * per > slab_budget) ys /= 3;
        int kpb = (KPv + ys - 1) / ys;
        long slab_elems = (long)l.nout * l.co;
        dim3 grid(blocks, (unsigned)ys);
        const float* bn = (const float*)d_in[2 * l.wi + 1];
        const u16* fh = ph[cset];
        const u16* fl = pl[cset];
        const u16* whp = (i >= 3) ? wth + woff[i - 3] : nullptr;
        const u16* wlp = (i >= 3) ? wtl + woff[i - 3] : nullptr;

        #define MCONV(CI_, CO_, RW_, KP_, KT_, PRD_, WH_, WL_)                         \
            do {                                                                       \
                if (ys == 1 && i < 11)                                                 \
                    mconv_kernel<CI_, CO_, RW_, KP_, KT_, PRD_, 1><<<grid, 256, 0, stream>>>( \
                        fh, fl, WH_, WL_, invp, zpage, nullptr, 0, bn,                 \
                        ph[cset ^ 1], pl[cset ^ 1], nullptr, l.nout, kpb);             \
                else if (ys == 1)                                                      \
                    mconv_kernel<CI_, CO_, RW_, KP_, KT_, PRD_, 2><<<grid, 256, 0, stream>>>( \
                        fh, fl, WH_, WL_, invp, zpage, nullptr, 0, bn,                 \
                        nullptr, nullptr, bufA, l.nout, kpb);                          \
                else                                                                   \
                    mconv_kernel<CI_, CO_, RW_, KP_, KT_, PRD_, 0><<<grid, 256, 0, stream>>>( \
                        fh, fl, WH_, WL_, invp, zpage, slab, slab_elems, bn,           \
                        nullptr, nullptr, nullptr, l.nout, kpb);                       \
            } while (0)

        switch (i) {
        case 1:          MCONV(32, 16, 64, 14, 27, true,  wp1h, wp1l); break;
        case 2:          MCONV(32, 32, 64, 14, 27, true,  wp2h, wp2l); break;
        case 3: case 4:  MCONV(32, 32, 64, 27, 27, false, whp, wlp);   break;
        case 5:          MCONV(32, 64, 128, 27, 27, false, whp, wlp);  break;
        case 11:         MCONV(64, 128, 64, 3, 3,  false, whp, wlp);   break;
        default:         MCONV(64, 64, 128, 27, 27, false, whp, wlp);  break;
        }
        #undef MCONV

        if (ys == 1) {
            if (i < 11) cset ^= 1;
        } else {
            long total = (long)l.nout * l.co;
            unsigned rblocks = (unsigned)((total + TPB - 1) / TPB);
            if (i < 11) {
                reduce_bnrelu_kernel<true><<<dim3(rblocks), dim3(TPB), 0, stream>>>(
                    slab, slab_elems, ys, bn, l.co,
                    nullptr, ph[cset ^ 1], pl[cset ^ 1], total);
                cset ^= 1;
            } else {
                reduce_bnrelu_kernel<false><<<dim3(rblocks), dim3(TPB), 0, stream>>>(
                    slab, slab_elems, ys, bn, l.co, bufA, nullptr, nullptr, total);
            }
        }
    }

    // ---- segment max
    hipMemsetAsync(d_out, 0, (size_t)out_size * sizeof(float), stream);
    const int* bidx = (const int*)d_in[42];
    int nb = out_size / 128;
    segmax_kernel<<<dim3(128), dim3(256), 0, stream>>>(bufA, bidx, (float*)d_out, n5, nb);
}

// Round 14
// 406.390 us; speedup vs baseline: 1.1602x; 1.1602x over previous
//
#include <hip/hip_runtime.h>

#define TPB 256
typedef unsigned short u16;
typedef __attribute__((ext_vector_type(8))) short short8v;
typedef __attribute__((ext_vector_type(4))) float f32x4;

__device__ __forceinline__ u16 f2bf(float x) {
    unsigned u = __float_as_uint(x);
    return (u16)((u + 0x7FFFu + ((u >> 16) & 1u)) >> 16);
}
__device__ __forceinline__ float bf2f(u16 h) {
    return __uint_as_float(((unsigned)h) << 16);
}

// LDS 16B-chunk XOR swizzle (CS = chunks per row = CI/8).
template<int CS>
__device__ __forceinline__ int swzc(int r, int c) {
    constexpr int PH = (CS == 8) ? 0 : 1;
    return c ^ ((r >> PH) & (CS - 1));
}

// bijective XCD-contiguity swizzle (m204)
__device__ __forceinline__ int xcd_swz(int bid, int nwg) {
    int q = nwg >> 3, r = nwg & 7;
    int x = bid & 7, idx = bid >> 3;
    return (x < r ? x * (q + 1) : r * (q + 1) + (x - r) * q) + idx;
}

// async global->LDS, 16B per lane
__device__ __forceinline__ void gld16(const u16* g, u16* l) {
    __builtin_amdgcn_global_load_lds(
        (const __attribute__((address_space(1))) void*)g,
        (__attribute__((address_space(3))) void*)l, 16, 0, 0);
}

// ---- mean-VFE
__global__ void vfe_kernel(const float* __restrict__ voxels,
                           const int* __restrict__ nump,
                           float* __restrict__ x, int N) {
    int i = blockIdx.x * blockDim.x + threadIdx.x;
    if (i >= N * 4) return;
    int n = i >> 2, c = i & 3;
    const float* v = voxels + (long)n * 20 + c;
    float s = v[0] + v[4] + v[8] + v[12] + v[16];
    x[i] = s / fmaxf((float)nump[n], 1.0f);
}

// ---- fused invert-rulebook build, TAP-MAJOR inv: inv[k][out_row] = in_row.
// Within a tap, rout is ascending & dense -> near-contiguous stores
// (R13's [n_out][K] layout had 108B-strided scatter: 93 MB WRITE, 70 us).
struct IBE { const int* rin; const int* rout; int* inv; int P, K, n_in, n_out, KP; };
struct IBA { IBE e[8]; };
__global__ void inv_build_all_kernel(IBA a, long grand) {
    long t = (long)blockIdx.x * blockDim.x + threadIdx.x;
    if (t >= grand) return;
    #pragma unroll
    for (int i = 0; i < 8; ++i) {
        if (t < a.e[i].KP) {
            const IBE& E = a.e[i];
            int ii = E.rin[t];
            if (ii != E.n_in) {
                int k = (int)(t / E.P);
                E.inv[(long)k * E.n_out + E.rout[t]] = ii;
            }
            return;
        }
        t -= a.e[i].KP;
    }
}

// ---- fused weight prep: 9 standard + 2 paired entries, one dispatch.
struct WPE { const float* w; u16* oh; u16* ol; int K, ci, co, total, paired; };
struct WPA { WPE e[11]; };
__global__ void wprep_kernel(WPA a, long grand) {
    long t = (long)blockIdx.x * blockDim.x + threadIdx.x;
    if (t >= grand) return;
    #pragma unroll
    for (int i = 0; i < 11; ++i) {
        if (t < a.e[i].total) {
            const WPE& E = a.e[i];
            if (E.paired) {
                int p = (int)(t / (E.co * 32));
                int rem = (int)(t % (E.co * 32));
                int o = rem / 32, ci = rem % 32;
                int tap = 2 * p + (ci >> 4);
                float x = (tap < 27) ? E.w[((long)tap * 16 + (ci & 15)) * E.co + o] : 0.f;
                u16 h = f2bf(x);
                float lf = x - bf2f(h);
                int ch = ci >> 3, e = ci & 7;
                int sch = ch ^ ((o >> 1) & 3);
                long d = ((long)p * E.co + o) * 32 + sch * 8 + e;
                E.oh[d] = h; E.ol[d] = f2bf(lf);
            } else {
                int cc = E.ci * E.co;
                int k = (int)(t / cc), r = (int)(t % cc), c = r / E.co, o = r % E.co;
                float x = E.w[t];
                u16 h = f2bf(x);
                float lf = x - bf2f(h);
                int cs = E.ci >> 3, ph = (cs == 8) ? 0 : 1;
                int ch = c >> 3, e = c & 7;
                int sch = ch ^ ((o >> ph) & (cs - 1));
                long d = ((long)k * E.co + o) * E.ci + sch * 8 + e;
                E.oh[d] = h; E.ol[d] = f2bf(lf);
            }
            return;
        }
        t -= a.e[i].total;
    }
}

// ---- direct tiny-CI conv (layer 0), emits bf16 hi/lo planes (tap-major inv)
template<int CO, int K>
__global__ __launch_bounds__(256)
void dconv4_kernel(const float* __restrict__ feats,
                   const float* __restrict__ w,
                   const float* __restrict__ bn,
                   const int* __restrict__ inv, int inv_n,
                   u16* __restrict__ oh, u16* __restrict__ ol,
                   int n_out) {
    constexpr int OG = CO / 4;
    __shared__ float sW[K * 4 * CO];
    for (int i = threadIdx.x; i < K * 4 * CO; i += 256) sW[i] = w[i];
    __syncthreads();
    long t = (long)blockIdx.x * 256 + threadIdx.x;
    int row = (int)(t / OG), og = (int)(t % OG);
    if (row >= n_out) return;
    float a0 = 0.f, a1 = 0.f, a2 = 0.f, a3 = 0.f;
    for (int k = 0; k < K; ++k) {
        int idx = inv[(long)k * inv_n + row];
        if (idx < 0) continue;
        float4 av = *(const float4*)(feats + (long)idx * 4);
        const float* wk = sW + k * 4 * CO + og * 4;
        #pragma unroll
        for (int ci = 0; ci < 4; ++ci) {
            float a = (&av.x)[ci];
            a0 = fmaf(a, wk[ci * CO + 0], a0);
            a1 = fmaf(a, wk[ci * CO + 1], a1);
            a2 = fmaf(a, wk[ci * CO + 2], a2);
            a3 = fmaf(a, wk[ci * CO + 3], a3);
        }
    }
    float4 g = *(const float4*)(bn + og * 4);
    float4 b = *(const float4*)(bn + CO + og * 4);
    float4 m = *(const float4*)(bn + 2 * CO + og * 4);
    float4 v = *(const float4*)(bn + 3 * CO + og * 4);
    float o4[4];
    o4[0] = fmaxf((a0 - m.x) * rsqrtf(v.x + 1e-3f) * g.x + b.x, 0.f);
    o4[1] = fmaxf((a1 - m.y) * rsqrtf(v.y + 1e-3f) * g.y + b.y, 0.f);
    o4[2] = fmaxf((a2 - m.z) * rsqrtf(v.z + 1e-3f) * g.z + b.z, 0.f);
    o4[3] = fmaxf((a3 - m.w) * rsqrtf(v.w + 1e-3f) * g.w + b.w, 0.f);
    long base = (long)row * CO + og * 4;
    #pragma unroll
    for (int c = 0; c < 4; ++c) {
        u16 h = f2bf(o4[c]);
        oh[base + c] = h;
        ol[base + c] = f2bf(o4[c] - bf2f(h));
    }
}

// ---- MFMA sparse conv: single-buffer gld16 staging, 2 barriers/tap,
// XOR-swizzled LDS, tap-major inv (contiguous 64-int read per tap).
// ROWS=64 (R12-proven; R13's ROWS=128 drove ys->27/kpb=1: slab traffic 3x).
// EPI: 0 = fp32 partials to slab; 1 = fused BN+ReLU+bf16 planes (ys==1);
// 2 = fused fp32 out.
template<int CI, int CO, int KPt, int KT, bool PAIRED, int EPI>
__global__ __launch_bounds__(256, 4)
void mconv_kernel(const u16* __restrict__ fh, const u16* __restrict__ fl,
                  const u16* __restrict__ wh, const u16* __restrict__ wl,
                  const int* __restrict__ inv,
                  const u16* __restrict__ zpage,
                  float* __restrict__ part, long slab_elems,
                  const float* __restrict__ bn,
                  u16* __restrict__ oh, u16* __restrict__ ol,
                  float* __restrict__ outf,
                  int n_out, int kpb) {
    constexpr int CS  = CI / 8;
    constexpr int LCS = (CS == 8) ? 3 : 2;
    constexpr int PH  = (CS == 8) ? 0 : 1;
    constexpr int KS  = CI / 32;
    constexpr int WC  = (CO >= 32) ? 2 : 1;
    constexpr int MT  = (WC == 2) ? 2 : 1;
    constexpr int NTW = CO / (16 * WC);
    constexpr int ASL = 64 * CS;
    constexpr int BSL = CO * CS;
    constexpr int AIT = (ASL + 255) / 256;
    constexpr int BIT = (BSL + 255) / 256;

    __shared__ __align__(16) u16 sAh[64 * CI];
    __shared__ __align__(16) u16 sAl[64 * CI];
    __shared__ __align__(16) u16 sBh[CO * CI];
    __shared__ __align__(16) u16 sBl[CO * CI];

    const int t = threadIdx.x;
    const int bx = xcd_swz(blockIdx.x, gridDim.x);
    const int brow = bx * 64;
    const int kbeg = blockIdx.y * kpb;
    const int kend = (kbeg + kpb < KPt) ? (kbeg + kpb) : KPt;

    const int lane = t & 63, wid = t >> 6;
    const int wr = wid / WC, wc = wid % WC;
    const int frow = lane & 15;
    const int fch  = lane >> 4;

    f32x4 acc[MT][NTW];
    #pragma unroll
    for (int mt = 0; mt < MT; ++mt)
        #pragma unroll
        for (int nt = 0; nt < NTW; ++nt) {
            acc[mt][nt][0] = 0.f; acc[mt][nt][1] = 0.f;
            acc[mt][nt][2] = 0.f; acc[mt][nt][3] = 0.f;
        }

    auto stage = [&](int k) {
        #pragma unroll
        for (int s = 0; s < AIT; ++s) {
            int slot = s * 256 + t;
            if (ASL % 256 == 0 || slot < ASL) {
                int r = slot >> LCS, cc = slot & (CS - 1);
                int c = cc ^ ((r >> PH) & (CS - 1));
                int grow = brow + r;
                const u16 *srcH, *srcL;
                if (PAIRED) {
                    int tap = 2 * k + (c >> 1);
                    int idx = (grow < n_out && tap < KT)
                              ? inv[(long)tap * n_out + grow] : -1;
                    srcH = (idx >= 0) ? fh + (long)idx * 16 + (c & 1) * 8 : zpage;
                    srcL = (idx >= 0) ? fl + (long)idx * 16 + (c & 1) * 8 : zpage;
                } else {
                    int idx = (grow < n_out) ? inv[(long)k * n_out + grow] : -1;
                    srcH = (idx >= 0) ? fh + (long)idx * CI + c * 8 : zpage;
                    srcL = (idx >= 0) ? fl + (long)idx * CI + c * 8 : zpage;
                }
                gld16(srcH, sAh + (s * 256 + wid * 64) * 8);
                gld16(srcL, sAl + (s * 256 + wid * 64) * 8);
            }
        }
        const u16* gbh = wh + (long)k * CO * CI;
        const u16* gbl = wl + (long)k * CO * CI;
        #pragma unroll
        for (int s = 0; s < BIT; ++s) {
            int slot = s * 256 + t;
            if (BSL % 256 == 0 || slot < BSL) {
                gld16(gbh + (long)slot * 8, sBh + (s * 256 + wid * 64) * 8);
                gld16(gbl + (long)slot * 8, sBl + (s * 256 + wid * 64) * 8);
            }
        }
    };
    auto compute = [&]() {
        #pragma unroll
        for (int ks = 0; ks < KS; ++ks) {
            int c = ks * 4 + fch;
            short8v ah[MT], al[MT];
            #pragma unroll
            for (int mt = 0; mt < MT; ++mt) {
                int r = wr * (MT * 16) + mt * 16 + frow;
                int o = r * CI + swzc<CS>(r, c) * 8;
                ah[mt] = *(const short8v*)(sAh + o);
                al[mt] = *(const short8v*)(sAl + o);
            }
            #pragma unroll
            for (int nt = 0; nt < NTW; ++nt) {
                int col = wc * (CO / WC) + nt * 16 + frow;
                int o = col * CI + swzc<CS>(col, c) * 8;
                short8v bh = *(const short8v*)(sBh + o);
                short8v bl = *(const short8v*)(sBl + o);
                #pragma unroll
                for (int mt = 0; mt < MT; ++mt) {
                    acc[mt][nt] = __builtin_amdgcn_mfma_f32_16x16x32_bf16(ah[mt], bh, acc[mt][nt], 0, 0, 0);
                    acc[mt][nt] = __builtin_amdgcn_mfma_f32_16x16x32_bf16(ah[mt], bl, acc[mt][nt], 0, 0, 0);
                    acc[mt][nt] = __builtin_amdgcn_mfma_f32_16x16x32_bf16(al[mt], bh, acc[mt][nt], 0, 0, 0);
                }
            }
        }
    };

    for (int k = kbeg; k < kend; ++k) {
        stage(k);
        __syncthreads();                        // drains vmcnt -> LDS staged
        compute();
        if (k + 1 < kend) __syncthreads();
    }

    if constexpr (EPI == 0) {
        float* dst = part + (long)blockIdx.y * slab_elems;
        #pragma unroll
        for (int mt = 0; mt < MT; ++mt) {
            int orow0 = brow + wr * (MT * 16) + mt * 16 + (lane >> 4) * 4;
            #pragma unroll
            for (int nt = 0; nt < NTW; ++nt) {
                int ocol = wc * (CO / WC) + nt * 16 + (lane & 15);
                #pragma unroll
                for (int j = 0; j < 4; ++j) {
                    int r = orow0 + j;
                    if (r < n_out) dst[(long)r * CO + ocol] = acc[mt][nt][j];
                }
            }
        }
    } else {
        #pragma unroll
        for (int mt = 0; mt < MT; ++mt) {
            int orow0 = brow + wr * (MT * 16) + mt * 16 + (lane >> 4) * 4;
            #pragma unroll
            for (int nt = 0; nt < NTW; ++nt) {
                int ocol = wc * (CO / WC) + nt * 16 + (lane & 15);
                float g = bn[ocol], bb = bn[CO + ocol];
                float m = bn[2 * CO + ocol], vv = bn[3 * CO + ocol];
                float sc = rsqrtf(vv + 1e-3f) * g;
                #pragma unroll
                for (int j = 0; j < 4; ++j) {
                    int r = orow0 + j;
                    if (r < n_out) {
                        float yv = fmaxf((acc[mt][nt][j] - m) * sc + bb, 0.f);
                        if constexpr (EPI == 1) {
                            u16 h = f2bf(yv);
                            oh[(long)r * CO + ocol] = h;
                            ol[(long)r * CO + ocol] = f2bf(yv - bf2f(h));
                        } else {
                            outf[(long)r * CO + ocol] = yv;
                        }
                    }
                }
            }
        }
    }
}

// ---- slab reduce + BN + ReLU (+ bf16 hi/lo emit OR fp32 out)
template<bool EMIT16>
__global__ void reduce_bnrelu_kernel(const float* __restrict__ part, long stride,
                                     int ys, const float* __restrict__ bn, int co,
                                     float* __restrict__ outf,
                                     u16* __restrict__ oh, u16* __restrict__ ol,
                                     long total) {
    long t = (long)blockIdx.x * blockDim.x + threadIdx.x;
    if (t >= total) return;
    float s = 0.f;
    for (int y = 0; y < ys; ++y) s += part[(long)y * stride + t];
    int o = (int)(t % co);
    float g = bn[o], b = bn[co + o], m = bn[2 * co + o], v = bn[3 * co + o];
    float yv = fmaxf((s - m) * rsqrtf(v + 1e-3f) * g + b, 0.f);
    if (EMIT16) {
        u16 h = f2bf(yv);
        oh[t] = h;
        ol[t] = f2bf(yv - bf2f(h));
    } else {
        outf[t] = yv;
    }
}

// ---- per-batch max pool
__global__ void segmax_kernel(const float* __restrict__ x,
                              const int* __restrict__ bidx,
                              float* __restrict__ out, int rows, int nb) {
    __shared__ float sM[8 * 128];
    for (int i = threadIdx.x; i < nb * 128; i += 256) sM[i] = 0.f;
    __syncthreads();
    int c = threadIdx.x & 127;
    int sub = threadIdx.x >> 7;
    for (int r = blockIdx.x * 2 + sub; r < rows; r += gridDim.x * 2) {
        float v = x[(long)r * 128 + c];
        int b = bidx[r];
        atomicMax((int*)&sM[b * 128 + c], __float_as_int(v));
    }
    __syncthreads();
    for (int i = threadIdx.x; i < nb * 128; i += 256)
        atomicMax((int*)out + i, __float_as_int(sM[i]));
}

extern "C" void kernel_launch(void* const* d_in, const int* in_sizes, int n_in,
                              void* d_out, int out_size, void* d_ws, size_t ws_size,
                              hipStream_t stream) {
    (void)n_in;
    const float* voxels = (const float*)d_in[24];
    const int*   nump   = (const int*)d_in[25];
    const int N  = in_sizes[25];
    const int n2 = in_sizes[30] / 27;
    const int n3 = in_sizes[34] / 27;
    const int n4 = in_sizes[38] / 27;
    const int n5 = in_sizes[42];

    struct L { int wi, rb, K, ci, co, nin, nout; };
    const L layers[12] = {
        {0,  26, 27,  4,  16, N,  N }, {1,  26, 27, 16,  16, N,  N },
        {2,  28, 27, 16,  32, N,  n2}, {3,  30, 27, 32,  32, n2, n2},
        {4,  30, 27, 32,  32, n2, n2}, {5,  32, 27, 32,  64, n2, n3},
        {6,  34, 27, 64,  64, n3, n3}, {7,  34, 27, 64,  64, n3, n3},
        {8,  36, 27, 64,  64, n3, n4}, {9,  38, 27, 64,  64, n4, n4},
        {10, 38, 27, 64,  64, n4, n4}, {11, 40,  3, 64, 128, n4, n5},
    };
    struct RBD { int rb, K, nin, nout; };
    const RBD rbs[8] = {
        {26, 27, N,  N }, {28, 27, N,  n2}, {30, 27, n2, n2}, {32, 27, n2, n3},
        {34, 27, n3, n3}, {36, 27, n3, n4}, {38, 27, n4, n4}, {40, 3,  n4, n5},
    };
    const int invmap[12] = {0, 0, 1, 2, 2, 3, 4, 4, 5, 6, 6, 7};

    // ---- workspace carve-up
    size_t feat_elems = (size_t)N * 4, wt_elems = 0, arena_elems = 0;
    for (int i = 0; i < 12; ++i) {
        size_t fe = (size_t)layers[i].nout * layers[i].co;
        if (fe > feat_elems) feat_elems = fe;
        if (i >= 3) wt_elems += (size_t)layers[i].K * layers[i].ci * layers[i].co;
    }
    for (int r = 0; r < 8; ++r) arena_elems += (size_t)rbs[r].nout * rbs[r].K;
    const size_t wp1_elems = 14 * 32 * 16;
    const size_t wp2_elems = 14 * 32 * 32;
    auto al = [](size_t x) { return (x + 255) & ~(size_t)255; };
    char* p = (char*)d_ws;
    u16*   zpage = (u16*)p; p += 256;
    int*   inv_arena = (int*)p; p += al(arena_elems * 4);
    float* bufA = (float*)p; p += al(feat_elems * 4);
    u16* ph[2]; u16* pl[2];
    ph[0] = (u16*)p; p += al(feat_elems * 2);
    pl[0] = (u16*)p; p += al(feat_elems * 2);
    ph[1] = (u16*)p; p += al(feat_elems * 2);
    pl[1] = (u16*)p; p += al(feat_elems * 2);
    u16* wth = (u16*)p; p += al(wt_elems * 2);
    u16* wtl = (u16*)p; p += al(wt_elems * 2);
    u16* wp1h = (u16*)p; p += al(wp1_elems * 2);
    u16* wp1l = (u16*)p; p += al(wp1_elems * 2);
    u16* wp2h = (u16*)p; p += al(wp2_elems * 2);
    u16* wp2l = (u16*)p; p += al(wp2_elems * 2);
    float* slab = (float*)p;
    size_t slab_budget = ws_size - (size_t)((char*)slab - (char*)d_ws);

    hipMemsetAsync(zpage, 0, 256, stream);

    // ---- inv arena: one memset + ONE fused build (tap-major)
    int* invs[8];
    {
        size_t off = 0;
        for (int r = 0; r < 8; ++r) { invs[r] = inv_arena + off; off += (size_t)rbs[r].nout * rbs[r].K; }
        hipMemsetAsync(inv_arena, 0xFF, arena_elems * sizeof(int), stream);
        IBA ia;
        long grand = 0;
        for (int r = 0; r < 8; ++r) {
            int P  = in_sizes[rbs[r].rb] / rbs[r].K;
            ia.e[r].rin  = (const int*)d_in[rbs[r].rb];
            ia.e[r].rout = (const int*)d_in[rbs[r].rb + 1];
            ia.e[r].inv  = invs[r];
            ia.e[r].P = P; ia.e[r].K = rbs[r].K; ia.e[r].n_in = rbs[r].nin;
            ia.e[r].n_out = rbs[r].nout;
            ia.e[r].KP = rbs[r].K * P;
            grand += ia.e[r].KP;
        }
        inv_build_all_kernel<<<dim3((unsigned)((grand + TPB - 1) / TPB)), dim3(TPB), 0, stream>>>(ia, grand);
    }

    // ---- VFE
    {
        long tot = (long)N * 4;
        vfe_kernel<<<dim3((unsigned)((tot + TPB - 1) / TPB)), dim3(TPB), 0, stream>>>(
            voxels, nump, bufA, N);
    }

    // ---- fused weight prep (9 standard + 2 paired)
    size_t woff[9];
    {
        WPA wa;
        size_t off = 0;
        for (int i = 0; i < 9; ++i) {
            const L& l = layers[i + 3];
            woff[i] = off;
            wa.e[i].w  = (const float*)d_in[2 * l.wi];
            wa.e[i].oh = wth + off;
            wa.e[i].ol = wtl + off;
            wa.e[i].K = l.K; wa.e[i].ci = l.ci; wa.e[i].co = l.co;
            wa.e[i].total = l.K * l.ci * l.co;
            wa.e[i].paired = 0;
            off += (size_t)wa.e[i].total;
        }
        wa.e[9]  = { (const float*)d_in[2], wp1h, wp1l, 27, 16, 16, (int)wp1_elems, 1 };
        wa.e[10] = { (const float*)d_in[4], wp2h, wp2l, 27, 16, 32, (int)wp2_elems, 1 };
        long grand = (long)off + wp1_elems + wp2_elems;
        wprep_kernel<<<dim3((unsigned)((grand + TPB - 1) / TPB)), dim3(TPB), 0, stream>>>(wa, grand);
    }

    // ---- layer 0
    {
        const L& l = layers[0];
        long tot = (long)l.nout * 4;
        dconv4_kernel<16, 27><<<dim3((unsigned)((tot + 255) / 256)), 256, 0, stream>>>(
            bufA, (const float*)d_in[0], (const float*)d_in[1], invs[0], l.nout,
            ph[0], pl[0], l.nout);
    }

    // ---- layers 1-11
    int cset = 0;
    for (int i = 1; i < 12; ++i) {
        const L& l = layers[i];
        const int* invp = invs[invmap[i]];
        unsigned blocks = (unsigned)((l.nout + 63) / 64);
        int KPv = (i <= 2) ? 14 : l.K;
        int ysmax = (KPv == 14) ? 9 : ((KPv == 27) ? 27 : 3);
        size_t per = (size_t)l.nout * l.co * 4;
        int ys = 1;
        while (ys < ysmax && blocks * (unsigned)ys < 768) ys *= 3;
        if (ys > ysmax) ys = ysmax;
        while (ys > 1 && (size_t)ys * per > slab_budget) ys /= 3;
        int kpb = (KPv + ys - 1) / ys;
        long slab_elems = (long)l.nout * l.co;
        dim3 grid(blocks, (unsigned)ys);
        const float* bn = (const float*)d_in[2 * l.wi + 1];
        const u16* fh = ph[cset];
        const u16* fl = pl[cset];
        const u16* whp = (i >= 3) ? wth + woff[i - 3] : nullptr;
        const u16* wlp = (i >= 3) ? wtl + woff[i - 3] : nullptr;

        #define MCONV(CI_, CO_, KP_, KT_, PRD_, WH_, WL_)                              \
            do {                                                                       \
                if (ys == 1 && i < 11)                                                 \
                    mconv_kernel<CI_, CO_, KP_, KT_, PRD_, 1><<<grid, 256, 0, stream>>>( \
                        fh, fl, WH_, WL_, invp, zpage, nullptr, 0, bn,                 \
                        ph[cset ^ 1], pl[cset ^ 1], nullptr, l.nout, kpb);             \
                else if (ys == 1)                                                      \
                    mconv_kernel<CI_, CO_, KP_, KT_, PRD_, 2><<<grid, 256, 0, stream>>>( \
                        fh, fl, WH_, WL_, invp, zpage, nullptr, 0, bn,                 \
                        nullptr, nullptr, bufA, l.nout, kpb);                          \
                else                                                                   \
                    mconv_kernel<CI_, CO_, KP_, KT_, PRD_, 0><<<grid, 256, 0, stream>>>( \
                        fh, fl, WH_, WL_, invp, zpage, slab, slab_elems, bn,           \
                        nullptr, nullptr, nullptr, l.nout, kpb);                       \
            } while (0)

        switch (i) {
        case 1:          MCONV(32, 16, 14, 27, true,  wp1h, wp1l); break;
        case 2:          MCONV(32, 32, 14, 27, true,  wp2h, wp2l); break;
        case 3: case 4:  MCONV(32, 32, 27, 27, false, whp, wlp);   break;
        case 5:          MCONV(32, 64, 27, 27, false, whp, wlp);   break;
        case 11:         MCONV(64, 128, 3, 3,  false, whp, wlp);   break;
        default:         MCONV(64, 64, 27, 27, false, whp, wlp);   break;
        }
        #undef MCONV

        if (ys == 1) {
            if (i < 11) cset ^= 1;
        } else {
            long total = (long)l.nout * l.co;
            unsigned rblocks = (unsigned)((total + TPB - 1) / TPB);
            if (i < 11) {
                reduce_bnrelu_kernel<true><<<dim3(rblocks), dim3(TPB), 0, stream>>>(
                    slab, slab_elems, ys, bn, l.co,
                    nullptr, ph[cset ^ 1], pl[cset ^ 1], total);
                cset ^= 1;
            } else {
                reduce_bnrelu_kernel<false><<<dim3(rblocks), dim3(TPB), 0, stream>>>(
                    slab, slab_elems, ys, bn, l.co, bufA, nullptr, nullptr, total);
            }
        }
    }

    // ---- segment max
    hipMemsetAsync(d_out, 0, (size_t)out_size * sizeof(float), stream);
    const int* bidx = (const int*)d_in[42];
    int nb = out_size / 128;
    segmax_kernel<<<dim3(128), dim3(256), 0, stream>>>(bufA, bidx, (float*)d_out, n5, nb);
}

// Round 15
// 390.029 us; speedup vs baseline: 1.2089x; 1.0419x over previous
//
#include <hip/hip_runtime.h>

#define TPB 256
typedef unsigned short u16;
typedef __attribute__((ext_vector_type(8))) short short8v;
typedef __attribute__((ext_vector_type(4))) float f32x4;

__device__ __forceinline__ u16 f2bf(float x) {
    unsigned u = __float_as_uint(x);
    return (u16)((u + 0x7FFFu + ((u >> 16) & 1u)) >> 16);
}
__device__ __forceinline__ float bf2f(u16 h) {
    return __uint_as_float(((unsigned)h) << 16);
}

// LDS 16B-chunk XOR swizzle (CS = chunks per row = CI/8).
template<int CS>
__device__ __forceinline__ int swzc(int r, int c) {
    constexpr int PH = (CS == 8) ? 0 : 1;
    return c ^ ((r >> PH) & (CS - 1));
}

// bijective XCD-contiguity swizzle (m204)
__device__ __forceinline__ int xcd_swz(int bid, int nwg) {
    int q = nwg >> 3, r = nwg & 7;
    int x = bid & 7, idx = bid >> 3;
    return (x < r ? x * (q + 1) : r * (q + 1) + (x - r) * q) + idx;
}

// async global->LDS, 16B per lane
__device__ __forceinline__ void gld16(const u16* g, u16* l) {
    __builtin_amdgcn_global_load_lds(
        (const __attribute__((address_space(1))) void*)g,
        (__attribute__((address_space(3))) void*)l, 16, 0, 0);
}

// ---- mean-VFE
__global__ void vfe_kernel(const float* __restrict__ voxels,
                           const int* __restrict__ nump,
                           float* __restrict__ x, int N) {
    int i = blockIdx.x * blockDim.x + threadIdx.x;
    if (i >= N * 4) return;
    int n = i >> 2, c = i & 3;
    const float* v = voxels + (long)n * 20 + c;
    float s = v[0] + v[4] + v[8] + v[12] + v[16];
    x[i] = s / fmaxf((float)nump[n], 1.0f);
}

// ---- fused invert-rulebook build, TAP-MAJOR inv: inv[k][out_row] = in_row.
struct IBE { const int* rin; const int* rout; int* inv; int P, K, n_in, n_out, KP; };
struct IBA { IBE e[8]; };
__global__ void inv_build_all_kernel(IBA a, long grand) {
    long t = (long)blockIdx.x * blockDim.x + threadIdx.x;
    if (t >= grand) return;
    #pragma unroll
    for (int i = 0; i < 8; ++i) {
        if (t < a.e[i].KP) {
            const IBE& E = a.e[i];
            int ii = E.rin[t];
            if (ii != E.n_in) {
                int k = (int)(t / E.P);
                E.inv[(long)k * E.n_out + E.rout[t]] = ii;
            }
            return;
        }
        t -= a.e[i].KP;
    }
}

// ---- fused weight prep: 7 standard (L5..L11) + 4 paired (L1..L4).
// standard: fp32 [K][ci][co] -> bf16 hi/lo [K][co][ci], swizzle baked in.
// paired (per-tap ci = pci): fp32 [27][pci][co] -> [14][co][2*pci],
// two taps concatenated on the reduction axis, pseudo-tap 13 second half
// zero, swizzle baked in (cs = 2*pci/8).
struct WPE { const float* w; u16* oh; u16* ol; int K, ci, co, total, pci; };
struct WPA { WPE e[11]; };
__global__ void wprep_kernel(WPA a, long grand) {
    long t = (long)blockIdx.x * blockDim.x + threadIdx.x;
    if (t >= grand) return;
    #pragma unroll
    for (int i = 0; i < 11; ++i) {
        if (t < a.e[i].total) {
            const WPE& E = a.e[i];
            if (E.pci) {
                int ci2 = 2 * E.pci;
                int p = (int)(t / (E.co * ci2));
                int rem = (int)(t % (E.co * ci2));
                int o = rem / ci2, ci = rem % ci2;
                int tap = 2 * p + ci / E.pci;
                float x = (tap < 27)
                    ? E.w[((long)tap * E.pci + (ci % E.pci)) * E.co + o] : 0.f;
                u16 h = f2bf(x);
                float lf = x - bf2f(h);
                int cs = ci2 >> 3, ph = (cs == 8) ? 0 : 1;
                int ch = ci >> 3, e = ci & 7;
                int sch = ch ^ ((o >> ph) & (cs - 1));
                long d = ((long)p * E.co + o) * ci2 + sch * 8 + e;
                E.oh[d] = h; E.ol[d] = f2bf(lf);
            } else {
                int cc = E.ci * E.co;
                int k = (int)(t / cc), r = (int)(t % cc), c = r / E.co, o = r % E.co;
                float x = E.w[t];
                u16 h = f2bf(x);
                float lf = x - bf2f(h);
                int cs = E.ci >> 3, ph = (cs == 8) ? 0 : 1;
                int ch = c >> 3, e = c & 7;
                int sch = ch ^ ((o >> ph) & (cs - 1));
                long d = ((long)k * E.co + o) * E.ci + sch * 8 + e;
                E.oh[d] = h; E.ol[d] = f2bf(lf);
            }
            return;
        }
        t -= a.e[i].total;
    }
}

// ---- direct tiny-CI conv (layer 0), emits bf16 hi/lo planes (tap-major inv)
template<int CO, int K>
__global__ __launch_bounds__(256)
void dconv4_kernel(const float* __restrict__ feats,
                   const float* __restrict__ w,
                   const float* __restrict__ bn,
                   const int* __restrict__ inv, int inv_n,
                   u16* __restrict__ oh, u16* __restrict__ ol,
                   int n_out) {
    constexpr int OG = CO / 4;
    __shared__ float sW[K * 4 * CO];
    for (int i = threadIdx.x; i < K * 4 * CO; i += 256) sW[i] = w[i];
    __syncthreads();
    long t = (long)blockIdx.x * 256 + threadIdx.x;
    int row = (int)(t / OG), og = (int)(t % OG);
    if (row >= n_out) return;
    float a0 = 0.f, a1 = 0.f, a2 = 0.f, a3 = 0.f;
    for (int k = 0; k < K; ++k) {
        int idx = inv[(long)k * inv_n + row];
        if (idx < 0) continue;
        float4 av = *(const float4*)(feats + (long)idx * 4);
        const float* wk = sW + k * 4 * CO + og * 4;
        #pragma unroll
        for (int ci = 0; ci < 4; ++ci) {
            float a = (&av.x)[ci];
            a0 = fmaf(a, wk[ci * CO + 0], a0);
            a1 = fmaf(a, wk[ci * CO + 1], a1);
            a2 = fmaf(a, wk[ci * CO + 2], a2);
            a3 = fmaf(a, wk[ci * CO + 3], a3);
        }
    }
    float4 g = *(const float4*)(bn + og * 4);
    float4 b = *(const float4*)(bn + CO + og * 4);
    float4 m = *(const float4*)(bn + 2 * CO + og * 4);
    float4 v = *(const float4*)(bn + 3 * CO + og * 4);
    float o4[4];
    o4[0] = fmaxf((a0 - m.x) * rsqrtf(v.x + 1e-3f) * g.x + b.x, 0.f);
    o4[1] = fmaxf((a1 - m.y) * rsqrtf(v.y + 1e-3f) * g.y + b.y, 0.f);
    o4[2] = fmaxf((a2 - m.z) * rsqrtf(v.z + 1e-3f) * g.z + b.z, 0.f);
    o4[3] = fmaxf((a3 - m.w) * rsqrtf(v.w + 1e-3f) * g.w + b.w, 0.f);
    long base = (long)row * CO + og * 4;
    #pragma unroll
    for (int c = 0; c < 4; ++c) {
        u16 h = f2bf(o4[c]);
        oh[base + c] = h;
        ol[base + c] = f2bf(o4[c] - bf2f(h));
    }
}

// ---- MFMA sparse conv: single-buffer gld16 staging, 2 barriers/tap,
// XOR-swizzled LDS, tap-major inv (contiguous per-tap reads). PAIRED:
// two real taps of width PCI concatenated per pseudo-tap (halves barrier
// chains). EPI: 0 = fp32 partials to slab; 1 = fused BN+ReLU+bf16 planes
// (ys==1); 2 = fused fp32 out.
template<int CI, int CO, int KPt, int KT, bool PAIRED, int PCI, int EPI>
__global__ __launch_bounds__(256, 4)
void mconv_kernel(const u16* __restrict__ fh, const u16* __restrict__ fl,
                  const u16* __restrict__ wh, const u16* __restrict__ wl,
                  const int* __restrict__ inv,
                  const u16* __restrict__ zpage,
                  float* __restrict__ part, long slab_elems,
                  const float* __restrict__ bn,
                  u16* __restrict__ oh, u16* __restrict__ ol,
                  float* __restrict__ outf,
                  int n_out, int kpb) {
    constexpr int CS  = CI / 8;
    constexpr int LCS = (CS == 8) ? 3 : 2;
    constexpr int PH  = (CS == 8) ? 0 : 1;
    constexpr int KS  = CI / 32;
    constexpr int WC  = (CO >= 32) ? 2 : 1;
    constexpr int MT  = (WC == 2) ? 2 : 1;
    constexpr int NTW = CO / (16 * WC);
    constexpr int ASL = 64 * CS;
    constexpr int BSL = CO * CS;
    constexpr int AIT = (ASL + 255) / 256;
    constexpr int BIT = (BSL + 255) / 256;
    constexpr int SUBCS = PAIRED ? (PCI / 8) : 1;   // chunks per sub-tap

    __shared__ __align__(16) u16 sAh[64 * CI];
    __shared__ __align__(16) u16 sAl[64 * CI];
    __shared__ __align__(16) u16 sBh[CO * CI];
    __shared__ __align__(16) u16 sBl[CO * CI];

    const int t = threadIdx.x;
    const int bx = xcd_swz(blockIdx.x, gridDim.x);
    const int brow = bx * 64;
    const int kbeg = blockIdx.y * kpb;
    const int kend = (kbeg + kpb < KPt) ? (kbeg + kpb) : KPt;

    const int lane = t & 63, wid = t >> 6;
    const int wr = wid / WC, wc = wid % WC;
    const int frow = lane & 15;
    const int fch  = lane >> 4;

    f32x4 acc[MT][NTW];
    #pragma unroll
    for (int mt = 0; mt < MT; ++mt)
        #pragma unroll
        for (int nt = 0; nt < NTW; ++nt) {
            acc[mt][nt][0] = 0.f; acc[mt][nt][1] = 0.f;
            acc[mt][nt][2] = 0.f; acc[mt][nt][3] = 0.f;
        }

    auto stage = [&](int k) {
        #pragma unroll
        for (int s = 0; s < AIT; ++s) {
            int slot = s * 256 + t;
            if (ASL % 256 == 0 || slot < ASL) {
                int r = slot >> LCS, cc = slot & (CS - 1);
                int c = cc ^ ((r >> PH) & (CS - 1));
                int grow = brow + r;
                const u16 *srcH, *srcL;
                if (PAIRED) {
                    int tap = 2 * k + c / SUBCS;
                    int within = c % SUBCS;
                    int idx = (grow < n_out && tap < KT)
                              ? inv[(long)tap * n_out + grow] : -1;
                    srcH = (idx >= 0) ? fh + (long)idx * PCI + within * 8 : zpage;
                    srcL = (idx >= 0) ? fl + (long)idx * PCI + within * 8 : zpage;
                } else {
                    int idx = (grow < n_out) ? inv[(long)k * n_out + grow] : -1;
                    srcH = (idx >= 0) ? fh + (long)idx * CI + c * 8 : zpage;
                    srcL = (idx >= 0) ? fl + (long)idx * CI + c * 8 : zpage;
                }
                gld16(srcH, sAh + (s * 256 + wid * 64) * 8);
                gld16(srcL, sAl + (s * 256 + wid * 64) * 8);
            }
        }
        const u16* gbh = wh + (long)k * CO * CI;
        const u16* gbl = wl + (long)k * CO * CI;
        #pragma unroll
        for (int s = 0; s < BIT; ++s) {
            int slot = s * 256 + t;
            if (BSL % 256 == 0 || slot < BSL) {
                gld16(gbh + (long)slot * 8, sBh + (s * 256 + wid * 64) * 8);
                gld16(gbl + (long)slot * 8, sBl + (s * 256 + wid * 64) * 8);
            }
        }
    };
    auto compute = [&]() {
        #pragma unroll
        for (int ks = 0; ks < KS; ++ks) {
            int c = ks * 4 + fch;
            short8v ah[MT], al[MT];
            #pragma unroll
            for (int mt = 0; mt < MT; ++mt) {
                int r = wr * (MT * 16) + mt * 16 + frow;
                int o = r * CI + swzc<CS>(r, c) * 8;
                ah[mt] = *(const short8v*)(sAh + o);
                al[mt] = *(const short8v*)(sAl + o);
            }
            #pragma unroll
            for (int nt = 0; nt < NTW; ++nt) {
                int col = wc * (CO / WC) + nt * 16 + frow;
                int o = col * CI + swzc<CS>(col, c) * 8;
                short8v bh = *(const short8v*)(sBh + o);
                short8v bl = *(const short8v*)(sBl + o);
                #pragma unroll
                for (int mt = 0; mt < MT; ++mt) {
                    acc[mt][nt] = __builtin_amdgcn_mfma_f32_16x16x32_bf16(ah[mt], bh, acc[mt][nt], 0, 0, 0);
                    acc[mt][nt] = __builtin_amdgcn_mfma_f32_16x16x32_bf16(ah[mt], bl, acc[mt][nt], 0, 0, 0);
                    acc[mt][nt] = __builtin_amdgcn_mfma_f32_16x16x32_bf16(al[mt], bh, acc[mt][nt], 0, 0, 0);
                }
            }
        }
    };

    for (int k = kbeg; k < kend; ++k) {
        stage(k);
        __syncthreads();
        compute();
        if (k + 1 < kend) __syncthreads();
    }

    if constexpr (EPI == 0) {
        float* dst = part + (long)blockIdx.y * slab_elems;
        #pragma unroll
        for (int mt = 0; mt < MT; ++mt) {
            int orow0 = brow + wr * (MT * 16) + mt * 16 + (lane >> 4) * 4;
            #pragma unroll
            for (int nt = 0; nt < NTW; ++nt) {
                int ocol = wc * (CO / WC) + nt * 16 + (lane & 15);
                #pragma unroll
                for (int j = 0; j < 4; ++j) {
                    int r = orow0 + j;
                    if (r < n_out) dst[(long)r * CO + ocol] = acc[mt][nt][j];
                }
            }
        }
    } else {
        #pragma unroll
        for (int mt = 0; mt < MT; ++mt) {
            int orow0 = brow + wr * (MT * 16) + mt * 16 + (lane >> 4) * 4;
            #pragma unroll
            for (int nt = 0; nt < NTW; ++nt) {
                int ocol = wc * (CO / WC) + nt * 16 + (lane & 15);
                float g = bn[ocol], bb = bn[CO + ocol];
                float m = bn[2 * CO + ocol], vv = bn[3 * CO + ocol];
                float sc = rsqrtf(vv + 1e-3f) * g;
                #pragma unroll
                for (int j = 0; j < 4; ++j) {
                    int r = orow0 + j;
                    if (r < n_out) {
                        float yv = fmaxf((acc[mt][nt][j] - m) * sc + bb, 0.f);
                        if constexpr (EPI == 1) {
                            u16 h = f2bf(yv);
                            oh[(long)r * CO + ocol] = h;
                            ol[(long)r * CO + ocol] = f2bf(yv - bf2f(h));
                        } else {
                            outf[(long)r * CO + ocol] = yv;
                        }
                    }
                }
            }
        }
    }
}

// ---- slab reduce + BN + ReLU, float4-vectorized (G13)
template<bool EMIT16>
__global__ void reduce_bnrelu_kernel(const float* __restrict__ part, long stride,
                                     int ys, const float* __restrict__ bn, int co,
                                     float* __restrict__ outf,
                                     u16* __restrict__ oh, u16* __restrict__ ol,
                                     long total4) {
    long t4 = (long)blockIdx.x * blockDim.x + threadIdx.x;
    if (t4 >= total4) return;
    long base = t4 * 4;
    float4 s = make_float4(0.f, 0.f, 0.f, 0.f);
    for (int y = 0; y < ys; ++y) {
        float4 v = *(const float4*)(part + (long)y * stride + base);
        s.x += v.x; s.y += v.y; s.z += v.z; s.w += v.w;
    }
    int o = (int)(base % co);                  // co % 4 == 0 -> o aligned
    float4 g = *(const float4*)(bn + o);
    float4 b = *(const float4*)(bn + co + o);
    float4 m = *(const float4*)(bn + 2 * co + o);
    float4 v = *(const float4*)(bn + 3 * co + o);
    float y0 = fmaxf((s.x - m.x) * rsqrtf(v.x + 1e-3f) * g.x + b.x, 0.f);
    float y1 = fmaxf((s.y - m.y) * rsqrtf(v.y + 1e-3f) * g.y + b.y, 0.f);
    float y2 = fmaxf((s.z - m.z) * rsqrtf(v.z + 1e-3f) * g.z + b.z, 0.f);
    float y3 = fmaxf((s.w - m.w) * rsqrtf(v.w + 1e-3f) * g.w + b.w, 0.f);
    if (EMIT16) {
        u16 h0 = f2bf(y0), h1 = f2bf(y1), h2 = f2bf(y2), h3 = f2bf(y3);
        ushort4 hv = { h0, h1, h2, h3 };
        ushort4 lv = { f2bf(y0 - bf2f(h0)), f2bf(y1 - bf2f(h1)),
                       f2bf(y2 - bf2f(h2)), f2bf(y3 - bf2f(h3)) };
        *(ushort4*)(oh + base) = hv;
        *(ushort4*)(ol + base) = lv;
    } else {
        *(float4*)(outf + base) = make_float4(y0, y1, y2, y3);
    }
}

// ---- per-batch max pool
__global__ void segmax_kernel(const float* __restrict__ x,
                              const int* __restrict__ bidx,
                              float* __restrict__ out, int rows, int nb) {
    __shared__ float sM[8 * 128];
    for (int i = threadIdx.x; i < nb * 128; i += 256) sM[i] = 0.f;
    __syncthreads();
    int c = threadIdx.x & 127;
    int sub = threadIdx.x >> 7;
    for (int r = blockIdx.x * 2 + sub; r < rows; r += gridDim.x * 2) {
        float v = x[(long)r * 128 + c];
        int b = bidx[r];
        atomicMax((int*)&sM[b * 128 + c], __float_as_int(v));
    }
    __syncthreads();
    for (int i = threadIdx.x; i < nb * 128; i += 256)
        atomicMax((int*)out + i, __float_as_int(sM[i]));
}

extern "C" void kernel_launch(void* const* d_in, const int* in_sizes, int n_in,
                              void* d_out, int out_size, void* d_ws, size_t ws_size,
                              hipStream_t stream) {
    (void)n_in;
    const float* voxels = (const float*)d_in[24];
    const int*   nump   = (const int*)d_in[25];
    const int N  = in_sizes[25];
    const int n2 = in_sizes[30] / 27;
    const int n3 = in_sizes[34] / 27;
    const int n4 = in_sizes[38] / 27;
    const int n5 = in_sizes[42];

    struct L { int wi, rb, K, ci, co, nin, nout; };
    const L layers[12] = {
        {0,  26, 27,  4,  16, N,  N }, {1,  26, 27, 16,  16, N,  N },
        {2,  28, 27, 16,  32, N,  n2}, {3,  30, 27, 32,  32, n2, n2},
        {4,  30, 27, 32,  32, n2, n2}, {5,  32, 27, 32,  64, n2, n3},
        {6,  34, 27, 64,  64, n3, n3}, {7,  34, 27, 64,  64, n3, n3},
        {8,  36, 27, 64,  64, n3, n4}, {9,  38, 27, 64,  64, n4, n4},
        {10, 38, 27, 64,  64, n4, n4}, {11, 40,  3, 64, 128, n4, n5},
    };
    struct RBD { int rb, K, nin, nout; };
    const RBD rbs[8] = {
        {26, 27, N,  N }, {28, 27, N,  n2}, {30, 27, n2, n2}, {32, 27, n2, n3},
        {34, 27, n3, n3}, {36, 27, n3, n4}, {38, 27, n4, n4}, {40, 3,  n4, n5},
    };
    const int invmap[12] = {0, 0, 1, 2, 2, 3, 4, 4, 5, 6, 6, 7};

    // ---- workspace carve-up
    size_t feat_elems = (size_t)N * 4, wst_elems = 0, arena_elems = 0;
    size_t wst_off[12];
    for (int i = 0; i < 12; ++i) {
        size_t fe = (size_t)layers[i].nout * layers[i].co;
        if (fe > feat_elems) feat_elems = fe;
        if (i >= 5) { wst_off[i] = wst_elems;
                      wst_elems += (size_t)layers[i].K * layers[i].ci * layers[i].co; }
    }
    for (int r = 0; r < 8; ++r) arena_elems += (size_t)rbs[r].nout * rbs[r].K;
    // paired buffers for L1..L4: [14][co][2*pci]
    const int pair_pci[4] = {16, 16, 32, 32};
    const int pair_co[4]  = {16, 32, 32, 32};
    size_t wpd_elems[4], wpd_off[4], wpd_tot = 0;
    for (int j = 0; j < 4; ++j) {
        wpd_elems[j] = (size_t)14 * pair_co[j] * 2 * pair_pci[j];
        wpd_off[j] = wpd_tot; wpd_tot += wpd_elems[j];
    }
    auto al = [](size_t x) { return (x + 255) & ~(size_t)255; };
    char* p = (char*)d_ws;
    u16*   zpage = (u16*)p; p += 256;
    int*   inv_arena = (int*)p; p += al(arena_elems * 4);
    float* bufA = (float*)p; p += al(feat_elems * 4);
    u16* ph[2]; u16* pl[2];
    ph[0] = (u16*)p; p += al(feat_elems * 2);
    pl[0] = (u16*)p; p += al(feat_elems * 2);
    ph[1] = (u16*)p; p += al(feat_elems * 2);
    pl[1] = (u16*)p; p += al(feat_elems * 2);
    u16* wth = (u16*)p; p += al(wst_elems * 2);
    u16* wtl = (u16*)p; p += al(wst_elems * 2);
    u16* wph = (u16*)p; p += al(wpd_tot * 2);
    u16* wpl = (u16*)p; p += al(wpd_tot * 2);
    float* slab = (float*)p;
    size_t slab_budget = ws_size - (size_t)((char*)slab - (char*)d_ws);

    hipMemsetAsync(zpage, 0, 256, stream);

    // ---- inv arena: one memset + one fused build (tap-major)
    int* invs[8];
    {
        size_t off = 0;
        for (int r = 0; r < 8; ++r) { invs[r] = inv_arena + off; off += (size_t)rbs[r].nout * rbs[r].K; }
        hipMemsetAsync(inv_arena, 0xFF, arena_elems * sizeof(int), stream);
        IBA ia;
        long grand = 0;
        for (int r = 0; r < 8; ++r) {
            int P  = in_sizes[rbs[r].rb] / rbs[r].K;
            ia.e[r].rin  = (const int*)d_in[rbs[r].rb];
            ia.e[r].rout = (const int*)d_in[rbs[r].rb + 1];
            ia.e[r].inv  = invs[r];
            ia.e[r].P = P; ia.e[r].K = rbs[r].K; ia.e[r].n_in = rbs[r].nin;
            ia.e[r].n_out = rbs[r].nout;
            ia.e[r].KP = rbs[r].K * P;
            grand += ia.e[r].KP;
        }
        inv_build_all_kernel<<<dim3((unsigned)((grand + TPB - 1) / TPB)), dim3(TPB), 0, stream>>>(ia, grand);
    }

    // ---- VFE
    {
        long tot = (long)N * 4;
        vfe_kernel<<<dim3((unsigned)((tot + TPB - 1) / TPB)), dim3(TPB), 0, stream>>>(
            voxels, nump, bufA, N);
    }

    // ---- fused weight prep: e[0..6] standard (L5..L11), e[7..10] paired (L1..L4)
    {
        WPA wa;
        long grand = 0;
        for (int i = 5; i < 12; ++i) {
            const L& l = layers[i];
            WPE& E = wa.e[i - 5];
            E.w  = (const float*)d_in[2 * l.wi];
            E.oh = wth + wst_off[i];
            E.ol = wtl + wst_off[i];
            E.K = l.K; E.ci = l.ci; E.co = l.co;
            E.total = l.K * l.ci * l.co;
            E.pci = 0;
            grand += E.total;
        }
        for (int j = 0; j < 4; ++j) {
            WPE& E = wa.e[7 + j];
            E.w  = (const float*)d_in[2 * layers[1 + j].wi];
            E.oh = wph + wpd_off[j];
            E.ol = wpl + wpd_off[j];
            E.K = 27; E.ci = pair_pci[j]; E.co = pair_co[j];
            E.total = (int)wpd_elems[j];
            E.pci = pair_pci[j];
            grand += E.total;
        }
        wprep_kernel<<<dim3((unsigned)((grand + TPB - 1) / TPB)), dim3(TPB), 0, stream>>>(wa, grand);
    }

    // ---- layer 0
    {
        const L& l = layers[0];
        long tot = (long)l.nout * 4;
        dconv4_kernel<16, 27><<<dim3((unsigned)((tot + 255) / 256)), 256, 0, stream>>>(
            bufA, (const float*)d_in[0], (const float*)d_in[1], invs[0], l.nout,
            ph[0], pl[0], l.nout);
    }

    // ---- layers 1-11
    int cset = 0;
    for (int i = 1; i < 12; ++i) {
        const L& l = layers[i];
        const int* invp = invs[invmap[i]];
        unsigned blocks = (unsigned)((l.nout + 63) / 64);
        int KPv = (i <= 4) ? 14 : l.K;
        int ysmax = (KPv == 14) ? 9 : ((KPv == 27) ? 27 : 3);
        size_t per = (size_t)l.nout * l.co * 4;
        int ys = 1;
        while (ys < ysmax && blocks * (unsigned)ys < 768) ys *= 3;
        if (ys > ysmax) ys = ysmax;
        while (ys > 1 && (size_t)ys * per > slab_budget) ys /= 3;
        int kpb = (KPv + ys - 1) / ys;
        long slab_elems = (long)l.nout * l.co;
        dim3 grid(blocks, (unsigned)ys);
        const float* bn = (const float*)d_in[2 * l.wi + 1];
        const u16* fh = ph[cset];
        const u16* fl = pl[cset];
        const u16* whp = (i >= 5) ? wth + wst_off[i] : wph + wpd_off[i - 1];
        const u16* wlp = (i >= 5) ? wtl + wst_off[i] : wpl + wpd_off[i - 1];

        #define MCONV(CI_, CO_, KP_, KT_, PRD_, PCI_)                                  \
            do {                                                                       \
                if (ys == 1 && i < 11)                                                 \
                    mconv_kernel<CI_, CO_, KP_, KT_, PRD_, PCI_, 1><<<grid, 256, 0, stream>>>( \
                        fh, fl, whp, wlp, invp, zpage, nullptr, 0, bn,                 \
                        ph[cset ^ 1], pl[cset ^ 1], nullptr, l.nout, kpb);             \
                else if (ys == 1)                                                      \
                    mconv_kernel<CI_, CO_, KP_, KT_, PRD_, PCI_, 2><<<grid, 256, 0, stream>>>( \
                        fh, fl, whp, wlp, invp, zpage, nullptr, 0, bn,                 \
                        nullptr, nullptr, bufA, l.nout, kpb);                          \
                else                                                                   \
                    mconv_kernel<CI_, CO_, KP_, KT_, PRD_, PCI_, 0><<<grid, 256, 0, stream>>>( \
                        fh, fl, whp, wlp, invp, zpage, slab, slab_elems, bn,           \
                        nullptr, nullptr, nullptr, l.nout, kpb);                       \
            } while (0)

        switch (i) {
        case 1:          MCONV(32, 16, 14, 27, true, 16);  break;
        case 2:          MCONV(32, 32, 14, 27, true, 16);  break;
        case 3: case 4:  MCONV(64, 32, 14, 27, true, 32);  break;
        case 5:          MCONV(32, 64, 27, 27, false, 32); break;
        case 11:         MCONV(64, 128, 3, 3, false, 64);  break;
        default:         MCONV(64, 64, 27, 27, false, 64); break;
        }
        #undef MCONV

        if (ys == 1) {
            if (i < 11) cset ^= 1;
        } else {
            long total4 = ((long)l.nout * l.co) / 4;
            unsigned rblocks = (unsigned)((total4 + TPB - 1) / TPB);
            if (i < 11) {
                reduce_bnrelu_kernel<true><<<dim3(rblocks), dim3(TPB), 0, stream>>>(
                    slab, slab_elems, ys, bn, l.co,
                    nullptr, ph[cset ^ 1], pl[cset ^ 1], total4);
                cset ^= 1;
            } else {
                reduce_bnrelu_kernel<false><<<dim3(rblocks), dim3(TPB), 0, stream>>>(
                    slab, slab_elems, ys, bn, l.co, bufA, nullptr, nullptr, total4);
            }
        }
    }

    // ---- segment max
    hipMemsetAsync(d_out, 0, (size_t)out_size * sizeof(float), stream);
    const int* bidx = (const int*)d_in[42];
    int nb = out_size / 128;
    segmax_kernel<<<dim3(128), dim3(256), 0, stream>>>(bufA, bidx, (float*)d_out, n5, nb);
}